// Round 4
// baseline (314.879 us; speedup 1.0000x reference)
//
#include <hip/hip_runtime.h>
#include <hip/hip_bf16.h>
#include <cstdint>

#define TPB 256
#define SCALE 0.17677669529663687f  // 32^-0.5

typedef float f4v __attribute__((ext_vector_type(4)));
typedef short s4v __attribute__((ext_vector_type(4)));
typedef short short8 __attribute__((ext_vector_type(8)));

__device__ __forceinline__ float b2f(short s){
  return __uint_as_float(((unsigned)(unsigned short)s) << 16);
}
__device__ __forceinline__ short f2b(float f){
  unsigned u = __float_as_uint(f);
  unsigned r = (u + 0x7fffu + ((u >> 16) & 1u)) >> 16;
  return (short)r;
}
__device__ __forceinline__ float geluf(float x){
  return 0.5f * x * (1.0f + erff(x * 0.7071067811865476f));
}
__device__ __forceinline__ f4v MFMA(short8 a, short8 b, f4v c){
  return __builtin_amdgcn_mfma_f32_16x16x32_bf16(a, b, c, 0, 0, 0);
}
// A-pattern fragment from row-major [*][ld]: row = rowBase+(l&15), k = kBase+8*(l>>4)
__device__ __forceinline__ short8 ldsA(const short* base, int ld, int rowBase, int kBase, int l){
  return *(const short8*)(base + (rowBase + (l & 15)) * ld + kBase + ((l >> 4) << 3));
}

// ws short-offsets
#define WEA_S   0
#define WSA_S   12288
#define FC11_S  24576
#define FC12_S  221184
#define FC2_S   417792
#define M11_S   434176
#define M12_S   450560
#define M2_S    466944
#define POS_S   483328
#define BIAS_B  970752      // bytes (float region)
#define YW_B    1048576     // bytes (bf16 y_win region)

// ---------------------------------------------------------------- prep ----
__global__ void prep(const float* __restrict__ wea, const float* __restrict__ wsa,
                     const float* __restrict__ fc11, const float* __restrict__ fc12,
                     const float* __restrict__ fc2,  const float* __restrict__ m11,
                     const float* __restrict__ m12,  const float* __restrict__ m2,
                     const float* __restrict__ rpb,
                     short* __restrict__ wsS, float* __restrict__ biasT)
{
  int gid = blockIdx.x * TPB + threadIdx.x;
  int stride = gridDim.x * TPB;
  for (int i = gid; i < 483328; i += stride){
    const float* src; int off;
    if      (i < 12288)  { src = wea;  off = i; }
    else if (i < 24576)  { src = wsa;  off = i - 12288; }
    else if (i < 221184) { src = fc11; off = i - 24576; }
    else if (i < 417792) { src = fc12; off = i - 221184; }
    else if (i < 434176) { src = fc2;  off = i - 417792; }
    else if (i < 450560) { src = m11;  off = i - 434176; }
    else if (i < 466944) { src = m12;  off = i - 450560; }
    else                 { src = m2;   off = i - 466944; }
    wsS[i] = f2b(src[off]);
  }
  if (gid < 16384){
    int h = gid >> 12, ij = gid & 4095, i = ij >> 6, j = ij & 63;
    int idx = ((i >> 3) - (j >> 3) + 7) * 15 + ((i & 7) - (j & 7) + 7);
    biasT[gid] = rpb[idx * 4 + h];
  }
  if (gid < 64){
    const float invT[8] = {1.f, 0.316227766f, 0.1f, 0.0316227766f,
                           0.01f, 0.00316227766f, 0.001f, 0.000316227766f};
    const float ANG = 6.28318530717958647692f / 8.000001f;
    float ay = (float)((gid >> 3) + 1) * ANG;
    float ax = (float)((gid & 7) + 1) * ANG;
    #pragma unroll
    for (int m = 0; m < 8; ++m){
      float s, cc;
      sincosf(ay * invT[m], &s, &cc);
      wsS[POS_S + gid*32 + 2*m]      = f2b(s);
      wsS[POS_S + gid*32 + 2*m + 1]  = f2b(cc);
      sincosf(ax * invT[m], &s, &cc);
      wsS[POS_S + gid*32 + 16 + 2*m] = f2b(s);
      wsS[POS_S + gid*32 + 17 + 2*m] = f2b(cc);
    }
  }
}

// -------------------------------------------------------------- kernel A --
struct SmemA {
  short xw[4][64][32];   // 16384 : LN'd tokens (later +pos in place)
  short K [64][136];     // 17408 : K, cols = e*32+c
  short VT[128][72];     // 18432 : V^T, rows = e*32+c, cols = token
  short SC[64][136];     // 17408 : scratch: Q strips / SA P,ych / abuf
  short P [64][72];      //  9216 : EA P strips (+ ych in cols 0..31)
};                       // 78848 B -> 2 WG/CU

// stage [16 rows of wave] x 32 cols at dst[..][colBase..]: C = X @ W[wRow..+32)^T
__device__ __forceinline__ void projRM(const short* X, const short* W, int wRow,
                                       short* dst, int dld, int colBase, float scl,
                                       int w, int l){
  short8 a = *(const short8*)(X + (w*16 + (l & 15))*32 + ((l >> 4) << 3));
  int row0 = w*16 + ((l >> 4) << 2);
  #pragma unroll
  for (int ct = 0; ct < 2; ++ct){
    short8 b = *(const short8*)(W + (wRow + ct*16 + (l & 15))*32 + ((l >> 4) << 3));
    f4v acc = {0.f,0.f,0.f,0.f};
    acc = MFMA(a, b, acc);
    int col = colBase + ct*16 + (l & 15);
    #pragma unroll
    for (int r = 0; r < 4; ++r) dst[(row0 + r)*dld + col] = f2b(acc[r] * scl);
  }
}

// stage transposed into VT[rowBase + c][token]
__device__ __forceinline__ void projVTn(const short* X, const short* W, int wRow,
                                        short* VT, int rowBase, int w, int l){
  short8 a = *(const short8*)(X + (w*16 + (l & 15))*32 + ((l >> 4) << 3));
  int tok0 = w*16 + ((l >> 4) << 2);
  #pragma unroll
  for (int ct = 0; ct < 2; ++ct){
    short8 b = *(const short8*)(W + (wRow + ct*16 + (l & 15))*32 + ((l >> 4) << 3));
    f4v acc = {0.f,0.f,0.f,0.f};
    acc = MFMA(a, b, acc);
    int f = rowBase + ct*16 + (l & 15);
    s4v pk;
    pk[0] = f2b(acc[0]); pk[1] = f2b(acc[1]); pk[2] = f2b(acc[2]); pk[3] = f2b(acc[3]);
    *(s4v*)(VT + f*72 + tok0) = pk;
  }
}

// softmax of s[4] (C-layout rows) + write P rows (wave strip) at dst stride dld
__device__ __forceinline__ void smaxP(f4v* s, const float* bias,
                                      short* dst, int dld, int w, int l){
  int row0 = w*16 + ((l >> 4) << 2);
  #pragma unroll
  for (int r = 0; r < 4; ++r){
    float v0 = s[0][r], v1 = s[1][r], v2 = s[2][r], v3 = s[3][r];
    if (bias){
      const float* bb = bias + (row0 + r)*64 + (l & 15);
      v0 += bb[0]; v1 += bb[16]; v2 += bb[32]; v3 += bb[48];
    }
    float m = fmaxf(fmaxf(v0, v1), fmaxf(v2, v3));
    m = fmaxf(m, __shfl_xor(m, 1));
    m = fmaxf(m, __shfl_xor(m, 2));
    m = fmaxf(m, __shfl_xor(m, 4));
    m = fmaxf(m, __shfl_xor(m, 8));
    float e0 = expf(v0 - m), e1 = expf(v1 - m);
    float e2 = expf(v2 - m), e3 = expf(v3 - m);
    float sum = e0 + e1 + e2 + e3;
    sum += __shfl_xor(sum, 1); sum += __shfl_xor(sum, 2);
    sum += __shfl_xor(sum, 4); sum += __shfl_xor(sum, 8);
    float inv = 1.0f / sum;
    short* pr = dst + (row0 + r)*dld + (l & 15);
    pr[0]  = f2b(e0 * inv);
    pr[16] = f2b(e1 * inv);
    pr[32] = f2b(e2 * inv);
    pr[48] = f2b(e3 * inv);
  }
}

// g1/g2 += A(strip rows, k=kb..kb+32) @ fc cols; B-frags straight from global
__device__ __forceinline__ void gegluK(const short* asrc, int ald, int kb,
                                       const short* fcA, const short* fcB, int cb,
                                       f4v* g1, f4v* g2, int w, int l){
  short8 a = *(const short8*)(asrc + (w*16 + (l & 15))*ald + kb + ((l >> 4) << 3));
  const short* pA = fcA + (l & 15)*1536 + cb + ((l >> 4) << 3);
  #pragma unroll
  for (int ct = 0; ct < 8; ++ct)
    g1[ct] = MFMA(a, *(const short8*)(pA + ct*16*1536), g1[ct]);
  const short* pB = fcB + (l & 15)*1536 + cb + ((l >> 4) << 3);
  #pragma unroll
  for (int ct = 0; ct < 8; ++ct)
    g2[ct] = MFMA(a, *(const short8*)(pB + ct*16*1536), g2[ct]);
}

__global__ __launch_bounds__(256, 2) void kernelA(
    const float* __restrict__ x,
    const float* __restrict__ ln1g, const float* __restrict__ ln1b,
    const float* __restrict__ fc11b_, const float* __restrict__ fc12b_,
    const float* __restrict__ fc2b_,
    const short* __restrict__ wsS, const float* __restrict__ biasT,
    short* __restrict__ yw)
{
  __shared__ SmemA sm;
  const int t = threadIdx.x, l = t & 63, w = t >> 6;
  const int bw = blockIdx.x, b = bw >> 8, hw = bw & 255, hi = hw >> 4, wj = hw & 15;
  const short* wea  = wsS + WEA_S;
  const short* wsa  = wsS + WSA_S;
  const short* fc11 = wsS + FC11_S;
  const short* fc12 = wsS + FC12_S;
  const short* fc2  = wsS + FC2_S;
  const short* posb = wsS + POS_S;
  const int row0 = w*16 + ((l >> 4) << 2);

  // ---- phase 0: window load + LayerNorm (mapping verified in rounds 1-2)
  {
    const int e = w, n = l;
    const int c = n >> 1, i0 = (n & 1) * 4;
    const float* src = x + ((size_t)((b*4 + e)*32 + c) * 128 + hi*8) * 128 + wj*8;
    float v[32];
    #pragma unroll
    for (int ii = 0; ii < 4; ++ii){
      f4v a  = *(const f4v*)(src + (size_t)(i0 + ii)*128);
      f4v bb = *(const f4v*)(src + (size_t)(i0 + ii)*128 + 4);
      v[ii*8+0]=a[0]; v[ii*8+1]=a[1]; v[ii*8+2]=a[2]; v[ii*8+3]=a[3];
      v[ii*8+4]=bb[0]; v[ii*8+5]=bb[1]; v[ii*8+6]=bb[2]; v[ii*8+7]=bb[3];
    }
    float mu = 0.f;
    #pragma unroll
    for (int k = 0; k < 32; ++k) mu += v[k];
    mu *= (1.f/32.f);
    float var = 0.f;
    #pragma unroll
    for (int k = 0; k < 32; ++k){ float d = v[k]-mu; var += d*d; }
    var *= (1.f/32.f);
    float rstd = rsqrtf(var + 1e-5f);
    #pragma unroll
    for (int c4 = 0; c4 < 8; ++c4){
      s4v sv;
      sv[0] = f2b((v[c4*4+0]-mu)*rstd*ln1g[c4*4+0] + ln1b[c4*4+0]);
      sv[1] = f2b((v[c4*4+1]-mu)*rstd*ln1g[c4*4+1] + ln1b[c4*4+1]);
      sv[2] = f2b((v[c4*4+2]-mu)*rstd*ln1g[c4*4+2] + ln1b[c4*4+2]);
      sv[3] = f2b((v[c4*4+3]-mu)*rstd*ln1g[c4*4+3] + ln1b[c4*4+3]);
      *(s4v*)&sm.xw[e][n][c4*4] = sv;
    }
  }

  f4v g1[8], g2[8];
  #pragma unroll
  for (int i = 0; i < 8; ++i){
    g1[i] = (f4v){0.f,0.f,0.f,0.f};
    g2[i] = (f4v){0.f,0.f,0.f,0.f};
  }

  // ==== SA branch: y cols [0,512) ====
  #pragma unroll 1
  for (int h = 0; h < 4; ++h){
    __syncthreads();   // phase0 visible (h=0) / WAR on K,VT (h>0)
    #pragma unroll
    for (int e = 0; e < 4; ++e){
      projRM (&sm.xw[e][0][0], wsa, 128 + h*32, &sm.K[0][0], 136, e*32, 1.0f, w, l);
      projVTn(&sm.xw[e][0][0], wsa, 256 + h*32, &sm.VT[0][0], e*32, w, l);
      projRM (&sm.xw[e][0][0], wsa,       h*32, &sm.SC[0][0], 136, e*32, SCALE, w, l);
    }
    __syncthreads();   // staging visible
    // S = Q @ K^T  (K-dim 128)
    f4v s[4];
    #pragma unroll
    for (int i = 0; i < 4; ++i) s[i] = (f4v){0.f,0.f,0.f,0.f};
    #pragma unroll
    for (int ks = 0; ks < 4; ++ks){
      short8 a = ldsA(&sm.SC[0][0], 136, w*16, ks*32, l);
      #pragma unroll
      for (int ct = 0; ct < 4; ++ct)
        s[ct] = MFMA(a, ldsA(&sm.K[0][0], 136, ct*16, ks*32, l), s[ct]);
    }
    smaxP(s, biasT + h*4096, &sm.SC[0][0], 136, w, l);   // P into SC strip (Q dead)
    // PV (all 128 f)
    f4v pv[8];
    #pragma unroll
    for (int i = 0; i < 8; ++i) pv[i] = (f4v){0.f,0.f,0.f,0.f};
    #pragma unroll
    for (int ks = 0; ks < 2; ++ks){
      short8 a = ldsA(&sm.SC[0][0], 136, w*16, ks*32, l);
      #pragma unroll
      for (int ct = 0; ct < 8; ++ct)
        pv[ct] = MFMA(a, ldsA(&sm.VT[0][0], 72, ct*16, ks*32, l), pv[ct]);
    }
    // ych into SC strip (P dead)
    #pragma unroll
    for (int ct = 0; ct < 8; ++ct)
      #pragma unroll
      for (int r = 0; r < 4; ++r)
        sm.SC[row0 + r][ct*16 + (l & 15)] = f2b(pv[ct][r]);
    // GEGLU accumulate, y cols h*128 .. h*128+128
    #pragma unroll
    for (int ks = 0; ks < 4; ++ks)
      gegluK(&sm.SC[0][0], 136, ks*32, fc11, fc12, h*128 + ks*32, g1, g2, w, l);
  }

  // ---- xw -> xw + pos (in place); wave w owns exposure w, thread l token l
  {
    const int e = w, n = l;
    #pragma unroll
    for (int c4 = 0; c4 < 8; ++c4){
      s4v xa = *(const s4v*)&sm.xw[e][n][c4*4];
      s4v pa = *(const s4v*)(posb + n*32 + c4*4);
      s4v o;
      #pragma unroll
      for (int j = 0; j < 4; ++j) o[j] = f2b(b2f(xa[j]) + b2f(pa[j]));
      *(s4v*)&sm.xw[e][n][c4*4] = o;
    }
  }

  // ==== EA branches: EA2 y cols [1024,1536), EA1 y cols [512,1024) ====
  #pragma unroll 1
  for (int h = 0; h < 4; ++h){
    __syncthreads();   // orders pos-add (h=0) / WAR on K,VT (h>0)
    #pragma unroll
    for (int e = 0; e < 4; ++e){
      projRM (&sm.xw[e][0][0], wea, 128 + h*32, &sm.K[0][0], 136, e*32, 1.0f, w, l);
      projVTn(&sm.xw[e][0][0], wea, 256 + h*32, &sm.VT[0][0], e*32, w, l);
      projRM (&sm.xw[e][0][0], wea,       h*32, &sm.SC[0][0], 136, e*32, SCALE, w, l);
    }
    __syncthreads();
    // EA2: attn(Qe, K0, V0)
    #pragma unroll
    for (int e = 0; e < 4; ++e){
      f4v s[4];
      #pragma unroll
      for (int i = 0; i < 4; ++i) s[i] = (f4v){0.f,0.f,0.f,0.f};
      short8 a = ldsA(&sm.SC[0][0], 136, w*16, e*32, l);
      #pragma unroll
      for (int ct = 0; ct < 4; ++ct)
        s[ct] = MFMA(a, ldsA(&sm.K[0][0], 136, ct*16, 0, l), s[ct]);
      smaxP(s, nullptr, &sm.P[0][0], 72, w, l);
      f4v pv[2] = {{0.f,0.f,0.f,0.f},{0.f,0.f,0.f,0.f}};
      #pragma unroll
      for (int ks = 0; ks < 2; ++ks){
        short8 ap = ldsA(&sm.P[0][0], 72, w*16, ks*32, l);
        #pragma unroll
        for (int ct = 0; ct < 2; ++ct)
          pv[ct] = MFMA(ap, ldsA(&sm.VT[0][0], 72, ct*16, ks*32, l), pv[ct]);
      }
      #pragma unroll
      for (int ct = 0; ct < 2; ++ct)
        #pragma unroll
        for (int r = 0; r < 4; ++r)
          sm.P[row0 + r][ct*16 + (l & 15)] = f2b(pv[ct][r]);   // ych in P strip
      gegluK(&sm.P[0][0], 72, 0, fc11, fc12, 1024 + h*128 + e*32, g1, g2, w, l);
      if (e == 0)
        gegluK(&sm.P[0][0], 72, 0, fc11, fc12, 512 + h*128, g1, g2, w, l);
    }
    // EA1: attn(Q0, Ke, Ve), e = 1..3
    #pragma unroll
    for (int e = 1; e < 4; ++e){
      f4v s[4];
      #pragma unroll
      for (int i = 0; i < 4; ++i) s[i] = (f4v){0.f,0.f,0.f,0.f};
      short8 a = ldsA(&sm.SC[0][0], 136, w*16, 0, l);
      #pragma unroll
      for (int ct = 0; ct < 4; ++ct)
        s[ct] = MFMA(a, ldsA(&sm.K[0][0], 136, ct*16, e*32, l), s[ct]);
      smaxP(s, nullptr, &sm.P[0][0], 72, w, l);
      f4v pv[2] = {{0.f,0.f,0.f,0.f},{0.f,0.f,0.f,0.f}};
      #pragma unroll
      for (int ks = 0; ks < 2; ++ks){
        short8 ap = ldsA(&sm.P[0][0], 72, w*16, ks*32, l);
        #pragma unroll
        for (int ct = 0; ct < 2; ++ct)
          pv[ct] = MFMA(ap, ldsA(&sm.VT[0][0], 72, e*32 + ct*16, ks*32, l), pv[ct]);
      }
      #pragma unroll
      for (int ct = 0; ct < 2; ++ct)
        #pragma unroll
        for (int r = 0; r < 4; ++r)
          sm.P[row0 + r][ct*16 + (l & 15)] = f2b(pv[ct][r]);
      gegluK(&sm.P[0][0], 72, 0, fc11, fc12, 512 + h*128 + e*32, g1, g2, w, l);
    }
  }

  __syncthreads();   // defensive: EA compute fully drained before epilogue reuse of SC

  // ---- epilogue (all wave-private): gelu -> SC strip; fc2; store y_win
  {
    #pragma unroll
    for (int ct = 0; ct < 8; ++ct){
      int o = ct*16 + (l & 15);
      float b1 = fc11b_[o], b2 = fc12b_[o];
      #pragma unroll
      for (int r = 0; r < 4; ++r)
        sm.SC[row0 + r][o] = f2b(geluf(g1[ct][r] + b1) * (g2[ct][r] + b2));
    }
    f4v z[8];
    #pragma unroll
    for (int i = 0; i < 8; ++i) z[i] = (f4v){0.f,0.f,0.f,0.f};
    #pragma unroll
    for (int ks = 0; ks < 4; ++ks){
      short8 a = ldsA(&sm.SC[0][0], 136, w*16, ks*32, l);
      const short* pB = fc2 + (l & 15)*128 + ks*32 + ((l >> 4) << 3);
      #pragma unroll
      for (int ct = 0; ct < 8; ++ct)
        z[ct] = MFMA(a, *(const short8*)(pB + ct*16*128), z[ct]);
    }
    short* ywb = yw + (size_t)bw * 8192;
    #pragma unroll
    for (int ct = 0; ct < 8; ++ct){
      int o = ct*16 + (l & 15);
      float bz = fc2b_[o];
      #pragma unroll
      for (int r = 0; r < 4; ++r)
        ywb[(row0 + r)*128 + o] = f2b(z[ct][r] + bz);
    }
  }
}

// -------------------------------------------------------------- kernel B --
struct SmemB {
  float x1t[128][132];   // 67584 : x1 = x + y  (native [ch][px])
  short xnt[128][136];   // 34816 : LN'd, px-major [px][ch]
  short ab[64][136];     // 17408 : GEGLU activations (per pass)
};                       // 119808 B

__global__ __launch_bounds__(256) void kernelB(
    const float* __restrict__ x,
    const float* __restrict__ ln2g, const float* __restrict__ ln2b,
    const float* __restrict__ m11b, const float* __restrict__ m12b,
    const float* __restrict__ m2b,
    const short* __restrict__ wsS, const short* __restrict__ yw,
    float* __restrict__ out)
{
  __shared__ SmemB sm;
  const int t = threadIdx.x, l = t & 63, w = t >> 6;
  const int b = blockIdx.x >> 7, rr = blockIdx.x & 127;
  const short* m11 = wsS + M11_S;
  const short* m12 = wsS + M12_S;
  const short* m2  = wsS + M2_S;
  const float* xb = x + (size_t)b * 128 * 16384 + (size_t)rr * 128;

  for (int fid = t; fid < 4096; fid += TPB){
    int ch = fid >> 5, q4 = fid & 31;
    *(f4v*)&sm.x1t[ch][q4*4] = *(const f4v*)(xb + (size_t)ch * 16384 + q4*4);
  }
  __syncthreads();
  {
    int q = t >> 1, hf = t & 1;
    const short* ys = yw + ((size_t)(b*256 + (rr & 15)*16 + (q & 15)) * 64
                            + (rr >> 4)*8 + (q >> 4)) * 128 + hf*64;
    #pragma unroll
    for (int k = 0; k < 64; ++k)
      sm.x1t[hf*64 + k][q] += b2f(ys[k]);
  }
  __syncthreads();
  {
    int q = t >> 1, hf = t & 1;
    float s = 0.f;
    for (int i = 0; i < 64; ++i) s += sm.x1t[hf*64 + i][q];
    s += __shfl_xor(s, 1);
    float mu = s * (1.f/128.f);
    float vv = 0.f;
    for (int i = 0; i < 64; ++i){ float d = sm.x1t[hf*64 + i][q] - mu; vv += d*d; }
    vv += __shfl_xor(vv, 1);
    float rstd = rsqrtf(vv * (1.f/128.f) + 1e-5f);
    for (int i4 = 0; i4 < 16; ++i4){
      s4v o;
      #pragma unroll
      for (int j = 0; j < 4; ++j){
        int ch = hf*64 + i4*4 + j;
        o[j] = f2b((sm.x1t[ch][q] - mu) * rstd * ln2g[ch] + ln2b[ch]);
      }
      *(s4v*)&sm.xnt[q][hf*64 + i4*4] = o;
    }
  }
  __syncthreads();
  for (int qb = 0; qb < 2; ++qb){
    int px0 = qb*64 + w*16;
    f4v G1[8], G2[8];
    #pragma unroll
    for (int i = 0; i < 8; ++i){
      G1[i] = (f4v){0.f,0.f,0.f,0.f};
      G2[i] = (f4v){0.f,0.f,0.f,0.f};
    }
    #pragma unroll
    for (int ks = 0; ks < 4; ++ks){
      short8 a = ldsA(&sm.xnt[0][0], 136, px0, ks*32, l);
      const short* p1 = m11 + (l & 15)*128 + ks*32 + ((l >> 4) << 3);
      #pragma unroll
      for (int ct = 0; ct < 8; ++ct)
        G1[ct] = MFMA(a, *(const short8*)(p1 + ct*16*128), G1[ct]);
      const short* p2 = m12 + (l & 15)*128 + ks*32 + ((l >> 4) << 3);
      #pragma unroll
      for (int ct = 0; ct < 8; ++ct)
        G2[ct] = MFMA(a, *(const short8*)(p2 + ct*16*128), G2[ct]);
    }
    int r0 = w*16 + ((l >> 4) << 2);
    #pragma unroll
    for (int ct = 0; ct < 8; ++ct){
      int o = ct*16 + (l & 15);
      float bb1 = m11b[o], bb2 = m12b[o];
      #pragma unroll
      for (int r = 0; r < 4; ++r)
        sm.ab[r0 + r][o] = f2b(geluf(G1[ct][r] + bb1) * (G2[ct][r] + bb2));
    }
    __syncthreads();
    f4v Z[8];
    #pragma unroll
    for (int i = 0; i < 8; ++i) Z[i] = (f4v){0.f,0.f,0.f,0.f};
    #pragma unroll
    for (int ks = 0; ks < 4; ++ks){
      short8 a = ldsA(&sm.ab[0][0], 136, w*16, ks*32, l);
      const short* pz = m2 + (l & 15)*128 + ks*32 + ((l >> 4) << 3);
      #pragma unroll
      for (int ct = 0; ct < 8; ++ct)
        Z[ct] = MFMA(a, *(const short8*)(pz + ct*16*128), Z[ct]);
    }
    #pragma unroll
    for (int ct = 0; ct < 8; ++ct){
      int ch = ct*16 + (l & 15);
      float bz = m2b[ch];
      #pragma unroll
      for (int r = 0; r < 4; ++r){
        int px = px0 + ((l >> 4) << 2) + r;
        sm.x1t[ch][px] += Z[ct][r] + bz;
      }
    }
    __syncthreads();
  }
  {
    int ch = t >> 1, qh = t & 1;
    float* ob = out + ((size_t)b*128 + ch) * 16384 + (size_t)rr * 128 + qh*64;
    #pragma unroll
    for (int q4 = 0; q4 < 16; ++q4)
      *(f4v*)(ob + q4*4) = *(const f4v*)&sm.x1t[ch][qh*64 + q4*4];
  }
}

extern "C" void kernel_launch(void* const* d_in, const int* in_sizes, int n_in,
                              void* d_out, int out_size, void* d_ws, size_t ws_size,
                              hipStream_t stream) {
  (void)in_sizes; (void)n_in; (void)out_size; (void)ws_size;
  const float* x     = (const float*)d_in[0];
  const float* ln1g  = (const float*)d_in[1];
  const float* ln1b  = (const float*)d_in[2];
  const float* wea   = (const float*)d_in[3];
  const float* wsa   = (const float*)d_in[4];
  const float* rpb   = (const float*)d_in[5];
  const float* fc11w = (const float*)d_in[6];
  const float* fc11b = (const float*)d_in[7];
  const float* fc12w = (const float*)d_in[8];
  const float* fc12b = (const float*)d_in[9];
  const float* fc2w  = (const float*)d_in[10];
  const float* fc2b  = (const float*)d_in[11];
  const float* ln2g  = (const float*)d_in[12];
  const float* ln2b  = (const float*)d_in[13];
  const float* m11w  = (const float*)d_in[14];
  const float* m11b  = (const float*)d_in[15];
  const float* m12w  = (const float*)d_in[16];
  const float* m12b  = (const float*)d_in[17];
  const float* m2w   = (const float*)d_in[18];
  const float* m2b   = (const float*)d_in[19];

  short* wsS   = (short*)d_ws;
  float* biasT = (float*)((char*)d_ws + BIAS_B);
  short* yw    = (short*)((char*)d_ws + YW_B);

  prep<<<1024, TPB, 0, stream>>>(wea, wsa, fc11w, fc12w, fc2w, m11w, m12w, m2w,
                                 rpb, wsS, biasT);
  kernelA<<<512, TPB, 0, stream>>>(x, ln1g, ln1b, fc11b, fc12b, fc2b,
                                   wsS, biasT, yw);
  kernelB<<<256, TPB, 0, stream>>>(x, ln2g, ln2b, m11b, m12b, m2b,
                                   wsS, yw, (float*)d_out);
}

// Round 5
// 245.370 us; speedup vs baseline: 1.2833x; 1.2833x over previous
//
#include <hip/hip_runtime.h>
#include <hip/hip_bf16.h>
#include <cstdint>

#define SCALE 0.17677669529663687f  // 32^-0.5

typedef float f4v __attribute__((ext_vector_type(4)));
typedef short s4v __attribute__((ext_vector_type(4)));
typedef short short8 __attribute__((ext_vector_type(8)));

__device__ __forceinline__ float b2f(short s){
  return __uint_as_float(((unsigned)(unsigned short)s) << 16);
}
__device__ __forceinline__ short f2b(float f){
  unsigned u = __float_as_uint(f);
  unsigned r = (u + 0x7fffu + ((u >> 16) & 1u)) >> 16;
  return (short)r;
}
__device__ __forceinline__ float geluf(float x){
  return 0.5f * x * (1.0f + erff(x * 0.7071067811865476f));
}
__device__ __forceinline__ f4v MFMA(short8 a, short8 b, f4v c){
  return __builtin_amdgcn_mfma_f32_16x16x32_bf16(a, b, c, 0, 0, 0);
}
// A/B-pattern fragment from row-major [*][ld]: row = rowBase+(l&15), k = kBase+8*(l>>4)
__device__ __forceinline__ short8 ldsA(const short* base, int ld, int rowBase, int kBase, int l){
  return *(const short8*)(base + (rowBase + (l & 15)) * ld + kBase + ((l >> 4) << 3));
}
// pack two C-layout f4v tiles into a bf16 operand fragment: slot k' = 4*tile + r
__device__ __forceinline__ short8 pack8(f4v a0, f4v a1, float scl){
  short8 o;
  #pragma unroll
  for (int k = 0; k < 4; ++k){
    o[k]     = f2b(a0[k] * scl);
    o[k + 4] = f2b(a1[k] * scl);
  }
  return o;
}
// token permutation for XTP storage: slot(n) matches P-pack positional pairing
__device__ __forceinline__ int permTok(int n){
  return (n & 32) | (((n >> 2) & 3) << 3) | (((n >> 4) & 1) << 2) | (n & 3);
}

// ws short-offsets
#define MTP_S   0         // 8 blks * 1024  (SA h0..3, EA h0..3; row-permuted M^T, SCALE folded)
#define FWP1_S  8192      // 48 blks * 4096 (fc11-blk * Wv, col-slot-permuted)
#define FWP2_S  204800    // 48 blks * 4096 (fc12)
#define FC2_S   401408    // 16384
#define M11_S   417792
#define M12_S   434176
#define M2_S    450560
#define POS_S   466944    // 2048
#define BIASP_B 937984    // bytes: 16384 f32, slot-permuted rel-pos bias
#define YW_B    1048576   // bytes: bf16 y_win region

// ---------------------------------------------------------------- prep ----
__global__ void prep(const float* __restrict__ wea, const float* __restrict__ wsa,
                     const float* __restrict__ fc11, const float* __restrict__ fc12,
                     const float* __restrict__ fc2,  const float* __restrict__ m11,
                     const float* __restrict__ m12,  const float* __restrict__ m2,
                     const float* __restrict__ rpb,
                     short* __restrict__ wsS, float* __restrict__ biasP)
{
  int gid = blockIdx.x * 256 + threadIdx.x;
  int stride = gridDim.x * 256;
  // FWP1 / FWP2: blk = br*16 + h*4 + e (br: 0=SA, 1=EA1, 2=EA2); [o][s], s=8*h4+k',
  // c(s) = 16*(k'>>2) + 4*h4 + (k'&3);  FW[o][c] = sum_f fc[o][cb+f] * Wv_h[f][c]
  for (int id = gid; id < 786432; id += stride){
    int isB = (id >= 393216);
    int i2 = isB ? id - 393216 : id;
    const float* fc = isB ? fc12 : fc11;
    int blk = i2 >> 12, rem = i2 & 4095;
    int o = rem >> 5, s = rem & 31;
    int h4 = (s >> 3) & 3, kp = s & 7;
    int c = 16*(kp >> 2) + 4*h4 + (kp & 3);
    int br = blk >> 4, h = (blk >> 2) & 3, e = blk & 3;
    int cb = h*128 + e*32 + (br == 0 ? 0 : (br == 1 ? 512 : 1024));
    const float* w = (br == 0) ? wsa : wea;
    float acc = 0.f;
    for (int f = 0; f < 32; ++f)
      acc += fc[o*1536 + cb + f] * w[(256 + h*32 + f)*32 + c];
    wsS[(isB ? FWP2_S : FWP1_S) + blk*4096 + o*32 + s] = f2b(acc);
  }
  // MTP: u = br*4 + h (br 0=SA wsa, 1=EA wea); row jp holds M^T row b = 8*h4+4*t+r
  for (int id = gid; id < 8192; id += stride){
    int u = id >> 10, jp = (id >> 5) & 31, a = id & 31;
    int h = u & 3;
    const float* w = (u < 4) ? wsa : wea;
    int t = jp >> 4, h4 = (jp >> 2) & 3, r = jp & 3;
    int b = 8*h4 + 4*t + r;
    float acc = 0.f;
    for (int d = 0; d < 32; ++d)
      acc += w[(h*32 + d)*32 + a] * w[(128 + h*32 + d)*32 + b];
    wsS[MTP_S + u*1024 + jp*32 + a] = f2b(acc * SCALE);
  }
  // plain bf16 copies
  for (int id = gid; id < 65536; id += stride){
    const float* src; int base; int off = id & 16383;
    switch (id >> 14){
      case 0:  src = fc2; base = FC2_S; break;
      case 1:  src = m11; base = M11_S; break;
      case 2:  src = m12; base = M12_S; break;
      default: src = m2;  base = M2_S;  break;
    }
    wsS[base + off] = f2b(src[off]);
  }
  // biasP[hh][i][h4][tj*4+r] = bias[i][j = tj*16 + 4*h4 + r]
  for (int id = gid; id < 16384; id += stride){
    int hh = id >> 12, i = (id >> 6) & 63, h4 = (id >> 4) & 3, tj = (id >> 2) & 3, r = id & 3;
    int j = tj*16 + 4*h4 + r;
    int idx = ((i >> 3) - (j >> 3) + 7)*15 + ((i & 7) - (j & 7) + 7);
    biasP[id] = rpb[idx*4 + hh];
  }
  // sine positional table (bf16, [n][c])
  if (gid < 64){
    const float invT[8] = {1.f, 0.316227766f, 0.1f, 0.0316227766f,
                           0.01f, 0.00316227766f, 0.001f, 0.000316227766f};
    const float ANG = 6.28318530717958647692f / 8.000001f;
    float ay = (float)((gid >> 3) + 1) * ANG;
    float ax = (float)((gid & 7) + 1) * ANG;
    #pragma unroll
    for (int m = 0; m < 8; ++m){
      float s, cc;
      sincosf(ay * invT[m], &s, &cc);
      wsS[POS_S + gid*32 + 2*m]      = f2b(s);
      wsS[POS_S + gid*32 + 2*m + 1]  = f2b(cc);
      sincosf(ax * invT[m], &s, &cc);
      wsS[POS_S + gid*32 + 16 + 2*m] = f2b(s);
      wsS[POS_S + gid*32 + 17 + 2*m] = f2b(cc);
    }
  }
}

// -------------------------------------------------------------- kernel A --
// LDS: xw[4][64][32] (8192 sh) UNION abuf[64][136] (8704 sh)  -> 8704
//      XTP[4][32][72] (9216 sh) UNION GBUF f32[64][132] (16896 sh) -> 16896
// total 25600 shorts = 51200 B -> 2 blocks/CU at 512 thr = 4 waves/SIMD
struct __align__(16) SmemA {
  short xw_ab[8704];
  short xtp_gb[16896];
};

// in-lane softmax over s[4] (16 values) + cross-lane (xor 16,32); s <- exp(s-m); returns 1/sum
__device__ __forceinline__ float smax16(f4v* s){
  float m = s[0][0];
  #pragma unroll
  for (int tj = 0; tj < 4; ++tj)
    #pragma unroll
    for (int r = 0; r < 4; ++r) m = fmaxf(m, s[tj][r]);
  m = fmaxf(m, __shfl_xor(m, 16));
  m = fmaxf(m, __shfl_xor(m, 32));
  float sum = 0.f;
  #pragma unroll
  for (int tj = 0; tj < 4; ++tj)
    #pragma unroll
    for (int r = 0; r < 4; ++r){
      float e = expf(s[tj][r] - m);
      s[tj][r] = e;
      sum += e;
    }
  sum += __shfl_xor(sum, 16);
  sum += __shfl_xor(sum, 32);
  return 1.0f / sum;
}

// Xq' pack: mfma(MTP rows, X rows of wave tile) -> permuted-row C-layout -> operand frag
__device__ __forceinline__ short8 projXq(const short* mtp, const short* xwE,
                                         int rho, int l){
  short8 xa = *(const short8*)(xwE + (rho*16 + (l & 15))*32 + ((l >> 4) << 3));
  f4v q0 = {0.f,0.f,0.f,0.f}, q1 = {0.f,0.f,0.f,0.f};
  q0 = MFMA(*(const short8*)(mtp + (l & 15)*32 + ((l >> 4) << 3)), xa, q0);
  q1 = MFMA(*(const short8*)(mtp + (16 + (l & 15))*32 + ((l >> 4) << 3)), xa, q1);
  return pack8(q0, q1, 1.f);
}

// g1/g2 += mfma(rp, FWP blk rows)
__device__ __forceinline__ void geglu16(short8 rp, const short* wsS, int blk,
                                        f4v* g1, f4v* g2, int l){
  const short* f1 = wsS + FWP1_S + blk*4096 + (l & 15)*32 + ((l >> 4) << 3);
  #pragma unroll
  for (int ct = 0; ct < 8; ++ct)
    g1[ct] = MFMA(rp, *(const short8*)(f1 + ct*512), g1[ct]);
  const short* f2 = wsS + FWP2_S + blk*4096 + (l & 15)*32 + ((l >> 4) << 3);
  #pragma unroll
  for (int ct = 0; ct < 8; ++ct)
    g2[ct] = MFMA(rp, *(const short8*)(f2 + ct*512), g2[ct]);
}

// softmax-tail of one attention unit: s[4] holds S^T tiles (pre-bias'd if needed)
__device__ __forceinline__ void unitTail(f4v* s, const short* xtpE, const short* wsS,
                                         int blk, int blkFold, f4v* g1, f4v* g2, int l){
  float inv = smax16(s);
  short8 pk0 = pack8(s[0], s[1], 1.f);
  short8 pk1 = pack8(s[2], s[3], 1.f);
  f4v rt0 = {0.f,0.f,0.f,0.f}, rt1 = {0.f,0.f,0.f,0.f};
  const short* x0 = xtpE + (l & 15)*72 + ((l >> 4) << 3);
  const short* x1 = xtpE + (16 + (l & 15))*72 + ((l >> 4) << 3);
  rt0 = MFMA(*(const short8*)(x0), pk0, rt0);
  rt0 = MFMA(*(const short8*)(x0 + 32), pk1, rt0);
  rt1 = MFMA(*(const short8*)(x1), pk0, rt1);
  rt1 = MFMA(*(const short8*)(x1 + 32), pk1, rt1);
  short8 rp = pack8(rt0, rt1, inv);
  geglu16(rp, wsS, blk, g1, g2, l);
  if (blkFold >= 0) geglu16(rp, wsS, blkFold, g1, g2, l);
}

__global__ __launch_bounds__(512, 4) void kernelA(
    const float* __restrict__ x,
    const float* __restrict__ ln1g, const float* __restrict__ ln1b,
    const float* __restrict__ fc11b_, const float* __restrict__ fc12b_,
    const float* __restrict__ fc2b_,
    const short* __restrict__ wsS, const float* __restrict__ biasP,
    short* __restrict__ yw)
{
  __shared__ SmemA sm;
  short* xw  = sm.xw_ab;    // [e][n][c] = e*2048 + n*32 + c
  short* ab  = sm.xw_ab;    // epilogue: [64][136]
  short* xtp = sm.xtp_gb;   // [e][c][pos] = e*2304 + c*72 + pos
  float* gb  = (float*)sm.xtp_gb;  // epilogue: [64][132]

  const int t = threadIdx.x, l = t & 63, w = t >> 6;
  const int tau = w >> 2, rho = w & 3;
  const int bw = blockIdx.x, b = bw >> 8, hw = bw & 255, hi = hw >> 4, wj = hw & 15;
  const int row0 = rho*16 + ((l >> 4) << 2);
  const short* posb = wsS + POS_S;

  // ---- phase 0: window load + LayerNorm. waves 0-3 -> xw; waves 4-7 -> XTP (token-permuted)
  {
    const int e = w & 3, n = l;
    const int c = n >> 1, i0 = (n & 1) * 4;
    const float* src = x + ((size_t)((b*4 + e)*32 + c) * 128 + hi*8) * 128 + wj*8;
    float v[32];
    #pragma unroll
    for (int ii = 0; ii < 4; ++ii){
      f4v a  = *(const f4v*)(src + (size_t)(i0 + ii)*128);
      f4v bb = *(const f4v*)(src + (size_t)(i0 + ii)*128 + 4);
      v[ii*8+0]=a[0]; v[ii*8+1]=a[1]; v[ii*8+2]=a[2]; v[ii*8+3]=a[3];
      v[ii*8+4]=bb[0]; v[ii*8+5]=bb[1]; v[ii*8+6]=bb[2]; v[ii*8+7]=bb[3];
    }
    float mu = 0.f;
    #pragma unroll
    for (int k = 0; k < 32; ++k) mu += v[k];
    mu *= (1.f/32.f);
    float var = 0.f;
    #pragma unroll
    for (int k = 0; k < 32; ++k){ float d = v[k]-mu; var += d*d; }
    var *= (1.f/32.f);
    float rstd = rsqrtf(var + 1e-5f);
    if (w < 4){
      #pragma unroll
      for (int c4 = 0; c4 < 8; ++c4){
        s4v sv;
        #pragma unroll
        for (int j = 0; j < 4; ++j)
          sv[j] = f2b((v[c4*4+j]-mu)*rstd*ln1g[c4*4+j] + ln1b[c4*4+j]);
        *(s4v*)&xw[e*2048 + n*32 + c4*4] = sv;
      }
    } else {
      int pn = permTok(n);
      #pragma unroll
      for (int c2 = 0; c2 < 32; ++c2)
        xtp[e*2304 + c2*72 + pn] = f2b((v[c2]-mu)*rstd*ln1g[c2] + ln1b[c2]);
    }
  }
  __syncthreads();

  f4v g1[8], g2[8];
  #pragma unroll
  for (int i = 0; i < 8; ++i){
    g1[i] = (f4v){0.f,0.f,0.f,0.f};
    g2[i] = (f4v){0.f,0.f,0.f,0.f};
  }

  // ==== SA: team tau handles hh = 2*tau + {0,1}; y cols [0,512) ====
  #pragma unroll 1
  for (int hx = 0; hx < 2; ++hx){
    const int hh = tau*2 + hx;
    const short* mtp = wsS + MTP_S + hh*1024;
    f4v s[4];
    #pragma unroll
    for (int i = 0; i < 4; ++i) s[i] = (f4v){0.f,0.f,0.f,0.f};
    #pragma unroll
    for (int e = 0; e < 4; ++e){
      short8 xq = projXq(mtp, xw + e*2048, rho, l);
      #pragma unroll
      for (int tj = 0; tj < 4; ++tj)
        s[tj] = MFMA(ldsA(xw + e*2048, 32, tj*16, 0, l), xq, s[tj]);
    }
    // rel-pos bias (slot-permuted): lane i = rho*16 + (l&15), group h4 = l>>4
    const float* bb = biasP + ((hh*64 + rho*16 + (l & 15))*4 + (l >> 4)) * 16;
    #pragma unroll
    for (int tj = 0; tj < 4; ++tj){
      f4v bv = *(const f4v*)(bb + tj*4);
      s[tj] += bv;
    }
    float inv = smax16(s);
    short8 pk0 = pack8(s[0], s[1], 1.f);
    short8 pk1 = pack8(s[2], s[3], 1.f);
    #pragma unroll 1
    for (int dc = 0; dc < 4; ++dc){
      const short* xt = xtp + dc*2304;
      f4v rt0 = {0.f,0.f,0.f,0.f}, rt1 = {0.f,0.f,0.f,0.f};
      const short* x0 = xt + (l & 15)*72 + ((l >> 4) << 3);
      const short* x1 = xt + (16 + (l & 15))*72 + ((l >> 4) << 3);
      rt0 = MFMA(*(const short8*)(x0), pk0, rt0);
      rt0 = MFMA(*(const short8*)(x0 + 32), pk1, rt0);
      rt1 = MFMA(*(const short8*)(x1), pk0, rt1);
      rt1 = MFMA(*(const short8*)(x1 + 32), pk1, rt1);
      short8 rp = pack8(rt0, rt1, inv);
      geglu16(rp, wsS, hh*4 + dc, g1, g2, l);
    }
  }

  // ---- xw/XTP -> +pos (in place)
  __syncthreads();
  {
    const int e = w & 3, n = l;
    if (w < 4){
      #pragma unroll
      for (int c4 = 0; c4 < 8; ++c4){
        s4v xa = *(const s4v*)&xw[e*2048 + n*32 + c4*4];
        s4v pa = *(const s4v*)(posb + n*32 + c4*4);
        s4v o;
        #pragma unroll
        for (int j = 0; j < 4; ++j) o[j] = f2b(b2f(xa[j]) + b2f(pa[j]));
        *(s4v*)&xw[e*2048 + n*32 + c4*4] = o;
      }
    } else {
      int pn = permTok(n);
      #pragma unroll
      for (int c2 = 0; c2 < 32; ++c2){
        int idx = e*2304 + c2*72 + pn;
        xtp[idx] = f2b(b2f(xtp[idx]) + b2f(posb[n*32 + c2]));
      }
    }
  }
  __syncthreads();

  // ==== EA: team tau handles hh = 2*tau + {0,1} ====
  #pragma unroll 1
  for (int hx = 0; hx < 2; ++hx){
    const int hh = tau*2 + hx;
    const short* mtp = wsS + MTP_S + (4 + hh)*1024;
    // EA2: attn(Qe, K0, V0) -> blk 32 + hh*4 + e; e==0 also folds EA1 blk 16 + hh*4
    #pragma unroll 1
    for (int e = 0; e < 4; ++e){
      short8 xq = projXq(mtp, xw + e*2048, rho, l);
      f4v s[4];
      #pragma unroll
      for (int i = 0; i < 4; ++i) s[i] = (f4v){0.f,0.f,0.f,0.f};
      #pragma unroll
      for (int tj = 0; tj < 4; ++tj)
        s[tj] = MFMA(ldsA(xw, 32, tj*16, 0, l), xq, s[tj]);
      unitTail(s, xtp, wsS, 32 + hh*4 + e, (e == 0) ? (16 + hh*4) : -1, g1, g2, l);
    }
    // EA1: attn(Q0, Ke, Ve) e=1..3 -> blk 16 + hh*4 + e
    short8 xq0 = projXq(mtp, xw, rho, l);
    #pragma unroll 1
    for (int e = 1; e < 4; ++e){
      f4v s[4];
      #pragma unroll
      for (int i = 0; i < 4; ++i) s[i] = (f4v){0.f,0.f,0.f,0.f};
      #pragma unroll
      for (int tj = 0; tj < 4; ++tj)
        s[tj] = MFMA(ldsA(xw + e*2048, 32, tj*16, 0, l), xq0, s[tj]);
      unitTail(s, xtp + e*2304, wsS, 16 + hh*4 + e, -1, g1, g2, l);
    }
  }

  // ==== epilogue: cross-team G-reduce, gelu, fc2, store y_win ====
  __syncthreads();              // all attention done; xw/XTP dead
  if (tau == 1){
    #pragma unroll
    for (int ct = 0; ct < 8; ++ct)
      #pragma unroll
      for (int r = 0; r < 4; ++r)
        gb[(row0 + r)*132 + ct*16 + (l & 15)] = g1[ct][r];
  }
  __syncthreads();
  if (tau == 0){
    #pragma unroll
    for (int ct = 0; ct < 8; ++ct)
      #pragma unroll
      for (int r = 0; r < 4; ++r)
        g1[ct][r] += gb[(row0 + r)*132 + ct*16 + (l & 15)];
  }
  __syncthreads();
  if (tau == 1){
    #pragma unroll
    for (int ct = 0; ct < 8; ++ct)
      #pragma unroll
      for (int r = 0; r < 4; ++r)
        gb[(row0 + r)*132 + ct*16 + (l & 15)] = g2[ct][r];
  }
  __syncthreads();
  if (tau == 0){
    #pragma unroll
    for (int ct = 0; ct < 8; ++ct){
      int o = ct*16 + (l & 15);
      float b1 = fc11b_[o], b2 = fc12b_[o];
      #pragma unroll
      for (int r = 0; r < 4; ++r){
        float h2 = g2[ct][r] + gb[(row0 + r)*132 + o] + b2;
        ab[(row0 + r)*136 + o] = f2b(geluf(g1[ct][r] + b1) * h2);
      }
    }
  }
  __syncthreads();
  {
    const short* fc2 = wsS + FC2_S;
    f4v z[4];
    #pragma unroll
    for (int i = 0; i < 4; ++i) z[i] = (f4v){0.f,0.f,0.f,0.f};
    #pragma unroll
    for (int ks = 0; ks < 4; ++ks){
      short8 a = ldsA(ab, 136, rho*16, ks*32, l);
      #pragma unroll
      for (int ctl = 0; ctl < 4; ++ctl){
        int ct2 = tau*4 + ctl;
        short8 bfrag = *(const short8*)(fc2 + (ct2*16 + (l & 15))*128 + ks*32 + ((l >> 4) << 3));
        z[ctl] = MFMA(a, bfrag, z[ctl]);
      }
    }
    short* ywb = yw + (size_t)bw * 8192;
    #pragma unroll
    for (int ctl = 0; ctl < 4; ++ctl){
      int o = (tau*4 + ctl)*16 + (l & 15);
      float bz = fc2b_[o];
      #pragma unroll
      for (int r = 0; r < 4; ++r)
        ywb[(row0 + r)*128 + o] = f2b(z[ctl][r] + bz);
    }
  }
}

// -------------------------------------------------------------- kernel B --
struct SmemB {
  float x1t[128][132];   // 67584 : x1 = x + y  (native [ch][px])
  short xnt[128][136];   // 34816 : LN'd, px-major [px][ch]
  short ab[64][136];     // 17408 : GEGLU activations (per pass)
};

__global__ __launch_bounds__(256) void kernelB(
    const float* __restrict__ x,
    const float* __restrict__ ln2g, const float* __restrict__ ln2b,
    const float* __restrict__ m11b, const float* __restrict__ m12b,
    const float* __restrict__ m2b,
    const short* __restrict__ wsS, const short* __restrict__ yw,
    float* __restrict__ out)
{
  __shared__ SmemB sm;
  const int t = threadIdx.x, l = t & 63, w = t >> 6;
  const int b = blockIdx.x >> 7, rr = blockIdx.x & 127;
  const short* m11 = wsS + M11_S;
  const short* m12 = wsS + M12_S;
  const short* m2  = wsS + M2_S;
  const float* xb = x + (size_t)b * 128 * 16384 + (size_t)rr * 128;

  for (int fid = t; fid < 4096; fid += 256){
    int ch = fid >> 5, q4 = fid & 31;
    *(f4v*)&sm.x1t[ch][q4*4] = *(const f4v*)(xb + (size_t)ch * 16384 + q4*4);
  }
  __syncthreads();
  {
    int q = t >> 1, hf = t & 1;
    const short* ys = yw + ((size_t)(b*256 + (rr & 15)*16 + (q & 15)) * 64
                            + (rr >> 4)*8 + (q >> 4)) * 128 + hf*64;
    #pragma unroll
    for (int k = 0; k < 64; ++k)
      sm.x1t[hf*64 + k][q] += b2f(ys[k]);
  }
  __syncthreads();
  {
    int q = t >> 1, hf = t & 1;
    float s = 0.f;
    for (int i = 0; i < 64; ++i) s += sm.x1t[hf*64 + i][q];
    s += __shfl_xor(s, 1);
    float mu = s * (1.f/128.f);
    float vv = 0.f;
    for (int i = 0; i < 64; ++i){ float d = sm.x1t[hf*64 + i][q] - mu; vv += d*d; }
    vv += __shfl_xor(vv, 1);
    float rstd = rsqrtf(vv * (1.f/128.f) + 1e-5f);
    for (int i4 = 0; i4 < 16; ++i4){
      s4v o;
      #pragma unroll
      for (int j = 0; j < 4; ++j){
        int ch = hf*64 + i4*4 + j;
        o[j] = f2b((sm.x1t[ch][q] - mu) * rstd * ln2g[ch] + ln2b[ch]);
      }
      *(s4v*)&sm.xnt[q][hf*64 + i4*4] = o;
    }
  }
  __syncthreads();
  for (int qb = 0; qb < 2; ++qb){
    int px0 = qb*64 + w*16;
    f4v G1[8], G2[8];
    #pragma unroll
    for (int i = 0; i < 8; ++i){
      G1[i] = (f4v){0.f,0.f,0.f,0.f};
      G2[i] = (f4v){0.f,0.f,0.f,0.f};
    }
    #pragma unroll
    for (int ks = 0; ks < 4; ++ks){
      short8 a = ldsA(&sm.xnt[0][0], 136, px0, ks*32, l);
      const short* p1 = m11 + (l & 15)*128 + ks*32 + ((l >> 4) << 3);
      #pragma unroll
      for (int ct = 0; ct < 8; ++ct)
        G1[ct] = MFMA(a, *(const short8*)(p1 + ct*16*128), G1[ct]);
      const short* p2 = m12 + (l & 15)*128 + ks*32 + ((l >> 4) << 3);
      #pragma unroll
      for (int ct = 0; ct < 8; ++ct)
        G2[ct] = MFMA(a, *(const short8*)(p2 + ct*16*128), G2[ct]);
    }
    int r0 = w*16 + ((l >> 4) << 2);
    #pragma unroll
    for (int ct = 0; ct < 8; ++ct){
      int o = ct*16 + (l & 15);
      float bb1 = m11b[o], bb2 = m12b[o];
      #pragma unroll
      for (int r = 0; r < 4; ++r)
        sm.ab[r0 + r][o] = f2b(geluf(G1[ct][r] + bb1) * (G2[ct][r] + bb2));
    }
    __syncthreads();
    f4v Z[8];
    #pragma unroll
    for (int i = 0; i < 8; ++i) Z[i] = (f4v){0.f,0.f,0.f,0.f};
    #pragma unroll
    for (int ks = 0; ks < 4; ++ks){
      short8 a = ldsA(&sm.ab[0][0], 136, w*16, ks*32, l);
      const short* pz = m2 + (l & 15)*128 + ks*32 + ((l >> 4) << 3);
      #pragma unroll
      for (int ct = 0; ct < 8; ++ct)
        Z[ct] = MFMA(a, *(const short8*)(pz + ct*16*128), Z[ct]);
    }
    #pragma unroll
    for (int ct = 0; ct < 8; ++ct){
      int ch = ct*16 + (l & 15);
      float bz = m2b[ch];
      #pragma unroll
      for (int r = 0; r < 4; ++r){
        int px = px0 + ((l >> 4) << 2) + r;
        sm.x1t[ch][px] += Z[ct][r] + bz;
      }
    }
    __syncthreads();
  }
  {
    int ch = t >> 1, qh = t & 1;
    float* ob = out + ((size_t)b*128 + ch) * 16384 + (size_t)rr * 128 + qh*64;
    #pragma unroll
    for (int q4 = 0; q4 < 16; ++q4)
      *(f4v*)(ob + q4*4) = *(const f4v*)&sm.x1t[ch][qh*64 + q4*4];
  }
}

extern "C" void kernel_launch(void* const* d_in, const int* in_sizes, int n_in,
                              void* d_out, int out_size, void* d_ws, size_t ws_size,
                              hipStream_t stream) {
  (void)in_sizes; (void)n_in; (void)out_size; (void)ws_size;
  const float* x     = (const float*)d_in[0];
  const float* ln1g  = (const float*)d_in[1];
  const float* ln1b  = (const float*)d_in[2];
  const float* wea   = (const float*)d_in[3];
  const float* wsa   = (const float*)d_in[4];
  const float* rpb   = (const float*)d_in[5];
  const float* fc11w = (const float*)d_in[6];
  const float* fc11b = (const float*)d_in[7];
  const float* fc12w = (const float*)d_in[8];
  const float* fc12b = (const float*)d_in[9];
  const float* fc2w  = (const float*)d_in[10];
  const float* fc2b  = (const float*)d_in[11];
  const float* ln2g  = (const float*)d_in[12];
  const float* ln2b  = (const float*)d_in[13];
  const float* m11w  = (const float*)d_in[14];
  const float* m11b  = (const float*)d_in[15];
  const float* m12w  = (const float*)d_in[16];
  const float* m12b  = (const float*)d_in[17];
  const float* m2w   = (const float*)d_in[18];
  const float* m2b   = (const float*)d_in[19];

  short* wsS   = (short*)d_ws;
  float* biasP = (float*)((char*)d_ws + BIASP_B);
  short* yw    = (short*)((char*)d_ws + YW_B);

  prep<<<1024, 256, 0, stream>>>(wea, wsa, fc11w, fc12w, fc2w, m11w, m12w, m2w,
                                 rpb, wsS, biasP);
  kernelA<<<512, 512, 0, stream>>>(x, ln1g, ln1b, fc11b, fc12b, fc2b,
                                   wsS, biasP, yw);
  kernelB<<<256, 256, 0, stream>>>(x, ln2g, ln2b, m11b, m12b, m2b,
                                   wsS, yw, (float*)d_out);
}